// Round 1
// baseline (3194.253 us; speedup 1.0000x reference)
//
#include <hip/hip_runtime.h>

constexpr int B = 4, C = 128, H = 192, W = 320;
constexpr int HW_ = H * W;

// ---------------------------------------------------------------------------
// 1) up_flow: depthwise transposed-conv (lhs_dilation=2, pad=2, k=4, flipped w)
//    computed in fp64 because it feeds floor()/mask decisions downstream.
// ---------------------------------------------------------------------------
__global__ __launch_bounds__(256) void upflow_kernel(
    const float* __restrict__ flow, const float* __restrict__ up_w,
    double* __restrict__ flow_up)
{
#pragma clang fp contract(off)
    int idx = blockIdx.x * 256 + threadIdx.x;
    if (idx >= B * 2 * HW_) return;
    int x = idx % W;
    int y = (idx / W) % H;
    int c = (idx / HW_) % 2;
    int b = idx / (2 * HW_);
    double acc = 0.0;
    #pragma unroll
    for (int ky = 0; ky < 4; ++ky) {
        int p = y + ky - 2;
        if (p < 0 || (p & 1) || (p >> 1) >= 96) continue;
        #pragma unroll
        for (int kx = 0; kx < 4; ++kx) {
            int q = x + kx - 2;
            if (q < 0 || (q & 1) || (q >> 1) >= 160) continue;
            double fv = (double)flow[((b * 2 + c) * 96 + (p >> 1)) * 160 + (q >> 1)];
            double wv = (double)up_w[c * 16 + (3 - ky) * 4 + (3 - kx)];
            double prod = fv * wv;
            acc = acc + prod;
        }
    }
    flow_up[idx] = acc;
}

// ---------------------------------------------------------------------------
// 2) warp: bilinear sample of feats[:,1] by flow_up*2.5 with oob mask.
//    Coordinate/mask math in fp64 replicating the reference op order exactly.
// ---------------------------------------------------------------------------
__global__ __launch_bounds__(256) void warp_kernel(
    const float* __restrict__ feats, const double* __restrict__ flow_up,
    float* __restrict__ warped)
{
#pragma clang fp contract(off)
    int idx = blockIdx.x * 256 + threadIdx.x;   // over B*H*W
    int x = idx % W;
    int y = (idx / W) % H;
    int b = idx / HW_;

    double f0 = flow_up[(size_t)(b * 2 + 0) * HW_ + y * W + x];
    double f1 = flow_up[(size_t)(b * 2 + 1) * HW_ + y * W + x];

    // linspace(-1,1,N) emulation (numpy: arange*delta + start, exact endpoint)
    double stepx = 2.0 / (double)(W - 1);
    double stepy = 2.0 / (double)(H - 1);
    double gx = (x == W - 1) ? 1.0 : ((double)x * stepx + (-1.0));
    double gy = (y == H - 1) ? 1.0 : ((double)y * stepy + (-1.0));
    double cxs = 2.0 * 2.5 / (double)(W - 1);
    double cys = 2.0 * 2.5 / (double)(H - 1);
    double sx = gx + f0 * cxs;
    double sy = gy + f1 * cys;
    double px = (sx + 1.0) * 0.5 * (double)(W - 1);
    double py = (sy + 1.0) * 0.5 * (double)(H - 1);

    double pxc = px < 0.0 ? 0.0 : (px > (double)(W - 1) ? (double)(W - 1) : px);
    double pyc = py < 0.0 ? 0.0 : (py > (double)(H - 1) ? (double)(H - 1) : py);
    double x0 = floor(pxc), y0 = floor(pyc);
    double tx = pxc - x0, ty = pyc - y0;
    int x0i = (int)x0, y0i = (int)y0;
    int x1i = min(x0i + 1, W - 1), y1i = min(y0i + 1, H - 1);

    // mask from UNclipped coords, in the reference's corner order
    double fx0 = floor(px), fy0 = floor(py);
    double mtx = px - fx0, mty = py - fy0;
    double omtx = 1.0 - mtx, omty = 1.0 - mty;
    double w00 = omtx * omty;
    double w01 = mtx * omty;
    double w10 = omtx * mty;
    double w11 = mtx * mty;
    double m = 0.0;
    double xi, yi;
    xi = fx0;       yi = fy0;
    if (xi >= 0.0 && xi <= (double)(W - 1) && yi >= 0.0 && yi <= (double)(H - 1)) m = m + w00;
    xi = fx0 + 1.0; yi = fy0;
    if (xi >= 0.0 && xi <= (double)(W - 1) && yi >= 0.0 && yi <= (double)(H - 1)) m = m + w01;
    xi = fx0;       yi = fy0 + 1.0;
    if (xi >= 0.0 && xi <= (double)(W - 1) && yi >= 0.0 && yi <= (double)(H - 1)) m = m + w10;
    xi = fx0 + 1.0; yi = fy0 + 1.0;
    if (xi >= 0.0 && xi <= (double)(W - 1) && yi >= 0.0 && yi <= (double)(H - 1)) m = m + w11;
    float mask = (m >= 1.0) ? 1.0f : 0.0f;

    float a00 = (float)((1.0 - tx) * (1.0 - ty)) * mask;
    float a01 = (float)(tx * (1.0 - ty)) * mask;
    float a10 = (float)((1.0 - tx) * ty) * mask;
    float a11 = (float)(tx * ty) * mask;

    int o00 = y0i * W + x0i;
    int o01 = y0i * W + x1i;
    int o10 = y1i * W + x0i;
    int o11 = y1i * W + x1i;
    const float* img = feats + (size_t)(b * 2 + 1) * C * HW_;
    float* dst = warped + (size_t)b * C * HW_ + y * W + x;
    for (int c = 0; c < C; ++c) {
        float v = a00 * img[o00] + a01 * img[o01] + a10 * img[o10] + a11 * img[o11];
        dst[(size_t)c * HW_] = v;
        img += HW_;
    }
}

// ---------------------------------------------------------------------------
// 3) correlation 7x7 (pad 3) + leaky(0.1) + /128 fused. 32x8 px tile per block.
// ---------------------------------------------------------------------------
__global__ __launch_bounds__(256) void corr_kernel(
    const float* __restrict__ feats, const float* __restrict__ warped,
    float* __restrict__ corr)
{
    __shared__ float tile[14 * 38];
    int t = blockIdx.x;
    int xt = t % 10, yt = (t / 10) % 24, b = t / 240;
    int tx0 = xt * 32, ty0 = yt * 8;
    int tid = threadIdx.x;
    int txl = tid & 31, tyl = tid >> 5;
    int x = tx0 + txl, y = ty0 + tyl;

    float acc[49];
    #pragma unroll
    for (int k = 0; k < 49; ++k) acc[k] = 0.f;

    const float* f1 = feats + (size_t)(b * 2) * C * HW_ + y * W + x;
    const float* wbase = warped + (size_t)b * C * HW_;

    for (int c = 0; c < C; ++c) {
        for (int s = tid; s < 14 * 38; s += 256) {
            int r = s / 38, cc = s - r * 38;
            int gy = ty0 + r - 3, gx = tx0 + cc - 3;
            float v = 0.f;
            if (gy >= 0 && gy < H && gx >= 0 && gx < W)
                v = wbase[(size_t)c * HW_ + gy * W + gx];
            tile[s] = v;
        }
        __syncthreads();
        float f1v = f1[(size_t)c * HW_];
        #pragma unroll
        for (int di = 0; di < 7; ++di)
            #pragma unroll
            for (int dj = 0; dj < 7; ++dj)
                acc[di * 7 + dj] += f1v * tile[(tyl + di) * 38 + txl + dj];
        __syncthreads();
    }
    float* outp = corr + (size_t)b * 49 * HW_ + y * W + x;
    #pragma unroll
    for (int k = 0; k < 49; ++k) {
        float v = acc[k];
        v = v > 0.f ? v : 0.1f * v;
        outp[(size_t)k * HW_] = v * (1.0f / 128.0f);
    }
}

// ---------------------------------------------------------------------------
// 4) generic direct conv: 32x8 spatial tile in LDS per cin, COPB outputs/thread,
//    weights via block-uniform loads (scalarize to s_load).
// ---------------------------------------------------------------------------
template <int CIN, int COPB, int KS, bool LEAKY, bool ADDFLOW>
__global__ __launch_bounds__(256) void conv_kernel(
    const float* __restrict__ in, const float* __restrict__ w,
    const float* __restrict__ bias, float* __restrict__ out,
    const double* __restrict__ flow_up, int coutTotal)
{
    constexpr int PADK = KS / 2;
    constexpr int ROWS = 8 + KS - 1;
    constexpr int COLS = 32 + KS - 1;
    __shared__ float tile[ROWS * COLS];

    int t = blockIdx.x;
    int xt = t % 10, yt = (t / 10) % 24, b = t / 240;
    int tx0 = xt * 32, ty0 = yt * 8;
    int tid = threadIdx.x;
    int txl = tid & 31, tyl = tid >> 5;
    int x = tx0 + txl, y = ty0 + tyl;

    float acc[COPB];
    #pragma unroll
    for (int i = 0; i < COPB; ++i) acc[i] = 0.f;
    int cob = blockIdx.y * COPB;
    const float* inb = in + (size_t)b * CIN * HW_;

    for (int cin = 0; cin < CIN; ++cin) {
        for (int s = tid; s < ROWS * COLS; s += 256) {
            int r = s / COLS, cc = s - r * COLS;
            int gy = ty0 + r - PADK, gx = tx0 + cc - PADK;
            float v = 0.f;
            if (gy >= 0 && gy < H && gx >= 0 && gx < W)
                v = inb[(size_t)cin * HW_ + gy * W + gx];
            tile[s] = v;
        }
        __syncthreads();
        float tv[KS * KS];
        #pragma unroll
        for (int ky = 0; ky < KS; ++ky)
            #pragma unroll
            for (int kx = 0; kx < KS; ++kx)
                tv[ky * KS + kx] = tile[(tyl + ky) * COLS + txl + kx];
        #pragma unroll
        for (int co = 0; co < COPB; ++co) {
            const float* wp = w + ((size_t)(cob + co) * CIN + cin) * KS * KS;
            #pragma unroll
            for (int kk = 0; kk < KS * KS; ++kk)
                acc[co] += wp[kk] * tv[kk];
        }
        __syncthreads();
    }
    #pragma unroll
    for (int co = 0; co < COPB; ++co) {
        float v = acc[co] + bias[cob + co];
        if constexpr (LEAKY) v = v > 0.f ? v : 0.1f * v;
        if constexpr (ADDFLOW)
            v += (float)flow_up[(size_t)(b * 2 + cob + co) * HW_ + y * W + x];
        out[((size_t)b * coutTotal + cob + co) * HW_ + y * W + x] = v;
    }
}

// ---------------------------------------------------------------------------
extern "C" void kernel_launch(void* const* d_in, const int* in_sizes, int n_in,
                              void* d_out, int out_size, void* d_ws, size_t ws_size,
                              hipStream_t stream)
{
    const float* feats = (const float*)d_in[0];
    const float* flow  = (const float*)d_in[1];
    const float* up_w  = (const float*)d_in[2];
    const float* w1 = (const float*)d_in[3];
    const float* b1 = (const float*)d_in[4];
    const float* w2 = (const float*)d_in[5];
    const float* b2 = (const float*)d_in[6];
    const float* w3 = (const float*)d_in[7];
    const float* b3 = (const float*)d_in[8];
    const float* w4 = (const float*)d_in[9];
    const float* b4 = (const float*)d_in[10];
    float* out = (float*)d_out;

    char* ws = (char*)d_ws;
    double* flow_up = (double*)ws;                              // 491520 f64 = 3.93 MB
    float* bufA = (float*)(ws + 3932160);                       // 31457280 f32 = 125.8 MB
    float* bufB = (float*)(ws + 3932160 + 125829120);           // 15728640 f32 = 62.9 MB

    upflow_kernel<<<(B * 2 * HW_ + 255) / 256, 256, 0, stream>>>(flow, up_w, flow_up);
    warp_kernel<<<(B * HW_) / 256, 256, 0, stream>>>(feats, flow_up, bufA);
    corr_kernel<<<960, 256, 0, stream>>>(feats, bufA, bufB);
    // conv head: corr(B,49)->h1(B,128)->h2(B,64)->h3(B,32)->new_flow(B,2)
    conv_kernel<49, 16, 3, true, false><<<dim3(960, 8), 256, 0, stream>>>(bufB, w1, b1, bufA, nullptr, 128);
    conv_kernel<128, 16, 3, true, false><<<dim3(960, 4), 256, 0, stream>>>(bufA, w2, b2, bufB, nullptr, 64);
    conv_kernel<64, 16, 3, true, false><<<dim3(960, 2), 256, 0, stream>>>(bufB, w3, b3, bufA, nullptr, 32);
    conv_kernel<32, 2, 5, false, true><<<dim3(960, 1), 256, 0, stream>>>(bufA, w4, b4, out, flow_up, 2);
}

// Round 2
// 1012.929 us; speedup vs baseline: 3.1535x; 3.1535x over previous
//
#include <hip/hip_runtime.h>

typedef __attribute__((ext_vector_type(8))) short short8;
typedef __attribute__((ext_vector_type(4))) float f32x4;
typedef __attribute__((ext_vector_type(4))) unsigned short ushort4v;

constexpr int B = 4, C = 128, H = 192, W = 320;
constexpr int HW_ = H * W;

__device__ __forceinline__ unsigned short f2bf(float x) {
    unsigned u = __float_as_uint(x);
    u += 0x7fffu + ((u >> 16) & 1u);
    return (unsigned short)(u >> 16);
}

// ---------------------------------------------------------------------------
// 1) up_flow in fp64 (feeds floor()/mask decisions downstream)
// ---------------------------------------------------------------------------
__global__ __launch_bounds__(256) void upflow_kernel(
    const float* __restrict__ flow, const float* __restrict__ up_w,
    double* __restrict__ flow_up)
{
#pragma clang fp contract(off)
    int idx = blockIdx.x * 256 + threadIdx.x;
    if (idx >= B * 2 * HW_) return;
    int x = idx % W;
    int y = (idx / W) % H;
    int c = (idx / HW_) % 2;
    int b = idx / (2 * HW_);
    double acc = 0.0;
    #pragma unroll
    for (int ky = 0; ky < 4; ++ky) {
        int p = y + ky - 2;
        if (p < 0 || (p & 1) || (p >> 1) >= 96) continue;
        #pragma unroll
        for (int kx = 0; kx < 4; ++kx) {
            int q = x + kx - 2;
            if (q < 0 || (q & 1) || (q >> 1) >= 160) continue;
            double fv = (double)flow[((b * 2 + c) * 96 + (p >> 1)) * 160 + (q >> 1)];
            double wv = (double)up_w[c * 16 + (3 - ky) * 4 + (3 - kx)];
            double prod = fv * wv;
            acc = acc + prod;
        }
    }
    flow_up[idx] = acc;
}

// ---------------------------------------------------------------------------
// 2) warp: bilinear + oob mask, coords in fp64 matching reference op order
// ---------------------------------------------------------------------------
__global__ __launch_bounds__(256) void warp_kernel(
    const float* __restrict__ feats, const double* __restrict__ flow_up,
    float* __restrict__ warped)
{
#pragma clang fp contract(off)
    int idx = blockIdx.x * 256 + threadIdx.x;   // over B*H*W
    int x = idx % W;
    int y = (idx / W) % H;
    int b = idx / HW_;

    double f0 = flow_up[(size_t)(b * 2 + 0) * HW_ + y * W + x];
    double f1 = flow_up[(size_t)(b * 2 + 1) * HW_ + y * W + x];

    double stepx = 2.0 / (double)(W - 1);
    double stepy = 2.0 / (double)(H - 1);
    double gx = (x == W - 1) ? 1.0 : ((double)x * stepx + (-1.0));
    double gy = (y == H - 1) ? 1.0 : ((double)y * stepy + (-1.0));
    double cxs = 2.0 * 2.5 / (double)(W - 1);
    double cys = 2.0 * 2.5 / (double)(H - 1);
    double sx = gx + f0 * cxs;
    double sy = gy + f1 * cys;
    double px = (sx + 1.0) * 0.5 * (double)(W - 1);
    double py = (sy + 1.0) * 0.5 * (double)(H - 1);

    double pxc = px < 0.0 ? 0.0 : (px > (double)(W - 1) ? (double)(W - 1) : px);
    double pyc = py < 0.0 ? 0.0 : (py > (double)(H - 1) ? (double)(H - 1) : py);
    double x0 = floor(pxc), y0 = floor(pyc);
    double tx = pxc - x0, ty = pyc - y0;
    int x0i = (int)x0, y0i = (int)y0;
    int x1i = min(x0i + 1, W - 1), y1i = min(y0i + 1, H - 1);

    double fx0 = floor(px), fy0 = floor(py);
    double mtx = px - fx0, mty = py - fy0;
    double w00 = (1.0 - mtx) * (1.0 - mty);
    double w01 = mtx * (1.0 - mty);
    double w10 = (1.0 - mtx) * mty;
    double w11 = mtx * mty;
    double m = 0.0;
    double xi, yi;
    xi = fx0;       yi = fy0;
    if (xi >= 0.0 && xi <= (double)(W - 1) && yi >= 0.0 && yi <= (double)(H - 1)) m = m + w00;
    xi = fx0 + 1.0; yi = fy0;
    if (xi >= 0.0 && xi <= (double)(W - 1) && yi >= 0.0 && yi <= (double)(H - 1)) m = m + w01;
    xi = fx0;       yi = fy0 + 1.0;
    if (xi >= 0.0 && xi <= (double)(W - 1) && yi >= 0.0 && yi <= (double)(H - 1)) m = m + w10;
    xi = fx0 + 1.0; yi = fy0 + 1.0;
    if (xi >= 0.0 && xi <= (double)(W - 1) && yi >= 0.0 && yi <= (double)(H - 1)) m = m + w11;
    float mask = (m >= 1.0) ? 1.0f : 0.0f;

    float a00 = (float)((1.0 - tx) * (1.0 - ty)) * mask;
    float a01 = (float)(tx * (1.0 - ty)) * mask;
    float a10 = (float)((1.0 - tx) * ty) * mask;
    float a11 = (float)(tx * ty) * mask;

    int o00 = y0i * W + x0i;
    int o01 = y0i * W + x1i;
    int o10 = y1i * W + x0i;
    int o11 = y1i * W + x1i;
    const float* img = feats + (size_t)(b * 2 + 1) * C * HW_;
    float* dst = warped + (size_t)b * C * HW_ + y * W + x;
    for (int c = 0; c < C; ++c) {
        float v = a00 * img[o00] + a01 * img[o01] + a10 * img[o10] + a11 * img[o11];
        dst[(size_t)c * HW_] = v;
        img += HW_;
    }
}

// ---------------------------------------------------------------------------
// 3) weight repack:  w -> [tap][coP][cinP] bf16, zero-padded
//    wr1 [9][128][64] | wr2 [9][64][128] | wr3 [9][32][64] | wr4 [25][16][32]
// ---------------------------------------------------------------------------
__global__ __launch_bounds__(256) void repack_w_kernel(
    const float* __restrict__ w1, const float* __restrict__ w2,
    const float* __restrict__ w3, const float* __restrict__ w4,
    unsigned short* __restrict__ wr)
{
    int idx = blockIdx.x * 256 + threadIdx.x;
    if (idx >= 178688) return;
    float v = 0.f;
    if (idx < 73728) {
        int tap = idx / 8192, r = idx % 8192, co = r / 64, ci = r % 64;
        if (ci < 49) v = w1[(co * 49 + ci) * 9 + tap];
    } else if (idx < 147456) {
        int i2 = idx - 73728;
        int tap = i2 / 8192, r = i2 % 8192, co = r / 128, ci = r % 128;
        v = w2[(co * 128 + ci) * 9 + tap];
    } else if (idx < 165888) {
        int i3 = idx - 147456;
        int tap = i3 / 2048, r = i3 % 2048, co = r / 64, ci = r % 64;
        v = w3[(co * 64 + ci) * 9 + tap];
    } else {
        int i4 = idx - 165888;
        int tap = i4 / 512, r = i4 % 512, co = r / 32, ci = r % 32;
        if (co < 2) v = w4[(co * 32 + ci) * 25 + tap];
    }
    wr[idx] = f2bf(v);
}

// ---------------------------------------------------------------------------
// 4) correlation: 8-channel chunks per barrier, bf16 64-ch padded output
// ---------------------------------------------------------------------------
__global__ __launch_bounds__(256) void corr_kernel(
    const float* __restrict__ feats, const float* __restrict__ warped,
    unsigned short* __restrict__ corr)
{
    __shared__ float tile[8 * 532];           // 8 cin x 14 x 38
    int t = blockIdx.x;
    int xt = t % 10, yt = (t / 10) % 24, b = t / 240;
    int tx0 = xt * 32, ty0 = yt * 8;
    int tid = threadIdx.x;
    int txl = tid & 31, tyl = tid >> 5;
    int x = tx0 + txl, y = ty0 + tyl;

    float acc[49];
    #pragma unroll
    for (int k = 0; k < 49; ++k) acc[k] = 0.f;

    const float* f1 = feats + (size_t)(b * 2) * C * HW_ + y * W + x;
    const float* wbase = warped + (size_t)b * C * HW_;

    for (int c0 = 0; c0 < C; c0 += 8) {
        float f1v[8];
        #pragma unroll
        for (int cc = 0; cc < 8; ++cc) f1v[cc] = f1[(size_t)(c0 + cc) * HW_];
        for (int s = tid; s < 8 * 532; s += 256) {
            int cc = s / 532, p = s % 532;
            int r = p / 38, col = p - r * 38;
            int gy = ty0 + r - 3, gx = tx0 + col - 3;
            float v = 0.f;
            if (gy >= 0 && gy < H && gx >= 0 && gx < W)
                v = wbase[(size_t)(c0 + cc) * HW_ + gy * W + gx];
            tile[s] = v;
        }
        __syncthreads();
        #pragma unroll
        for (int cc = 0; cc < 8; ++cc) {
            const float* tp = tile + cc * 532 + tyl * 38 + txl;
            #pragma unroll
            for (int di = 0; di < 7; ++di)
                #pragma unroll
                for (int dj = 0; dj < 7; ++dj)
                    acc[di * 7 + dj] += f1v[cc] * tp[di * 38 + dj];
        }
        __syncthreads();
    }
    unsigned short* outp = corr + (size_t)b * 64 * HW_ + y * W + x;
    #pragma unroll
    for (int k = 0; k < 49; ++k) {
        float v = acc[k];
        v = v > 0.f ? v : 0.1f * v;
        outp[(size_t)k * HW_] = f2bf(v * (1.0f / 128.0f));
    }
    #pragma unroll
    for (int k = 49; k < 64; ++k) outp[(size_t)k * HW_] = 0;
}

// ---------------------------------------------------------------------------
// 5) implicit-GEMM MFMA conv. LDS tile [pixel][cin] (16B-aligned stride),
//    per-tap accumulation: out += W[:,:,ky,kx] @ shifted tile.
//    Block = 4 waves; wave -> (m_idx, pgroup); wave computes 16co x N_TILES*16px.
// ---------------------------------------------------------------------------
template<int CINP, int CHUNK, int COUTP, int M_TILES, int N_TILES, int KS,
         bool LEAKY, bool ADDFLOW, bool OUTBF16>
__global__ __launch_bounds__(256) void conv_mfma_kernel(
    const unsigned short* __restrict__ in, const unsigned short* __restrict__ wr,
    const float* __restrict__ bias, void* __restrict__ outp,
    const double* __restrict__ flow_up, int coutReal)
{
    constexpr int PADK = KS / 2;
    constexpr int PX_GROUPS = 4 / M_TILES;
    constexpr int TH = PX_GROUPS * (N_TILES / 2);
    constexpr int RH = TH + KS - 1;
    constexpr int RW = 40;
    constexpr int STRIDE = CHUNK + 8;           // halfs; mult of 8 -> 16B aligned rows
    constexpr int KSTEPS = CHUNK / 32;
    constexpr int CHUNKS = CINP / CHUNK;
    __shared__ unsigned short lds[RH * RW * STRIDE];

    int tid = threadIdx.x;
    int lanelo = tid & 15, laneq = (tid >> 4) & 3, wave = tid >> 6;
    int m_idx = wave % M_TILES, pgroup = wave / M_TILES;
    int pg_row0 = pgroup * (N_TILES / 2);

    int bx = blockIdx.x;
    int xt = bx % 10;
    int yt = (bx / 10) % (H / TH);
    int b = bx / (10 * (H / TH));
    int tx0 = xt * 32, ty0 = yt * TH;
    int cob = blockIdx.y * (M_TILES * 16) + m_idx * 16;

    f32x4 acc[N_TILES];
    #pragma unroll
    for (int n = 0; n < N_TILES; ++n) acc[n] = f32x4{0.f, 0.f, 0.f, 0.f};

    const unsigned short* inb = in + (size_t)b * CINP * HW_;

    for (int ck = 0; ck < CHUNKS; ++ck) {
        // ---- stage chunk into LDS: [region px][cin] bf16 ----
        constexpr int UNITS = RH * 10 * (CHUNK / 2);
        for (int s = tid; s < UNITS; s += 256) {
            int r = s / (10 * (CHUNK / 2));
            int rem = s - r * (10 * (CHUNK / 2));
            int cp = rem / 10;
            int q = rem - cp * 10;
            int gy = ty0 - PADK + r;
            int gx0 = tx0 - 4 + q * 4;
            int c0 = ck * CHUNK + 2 * cp;
            ushort4v lo = {0, 0, 0, 0}, hi = {0, 0, 0, 0};
            if (gy >= 0 && gy < H && gx0 >= 0 && gx0 < W) {
                const unsigned short* p0 = inb + (size_t)c0 * HW_ + gy * W + gx0;
                lo = *(const ushort4v*)p0;
                hi = *(const ushort4v*)(p0 + HW_);
            }
            int pbase = (r * RW + q * 4) * STRIDE + 2 * cp;
            #pragma unroll
            for (int i = 0; i < 4; ++i) {
                unsigned v = (unsigned)lo[i] | ((unsigned)hi[i] << 16);
                *(unsigned*)&lds[pbase + i * STRIDE] = v;
            }
        }
        __syncthreads();

        // ---- A fragments (weights), one 16B global load each ----
        short8 afr[KS * KS * KSTEPS];
        #pragma unroll
        for (int tap = 0; tap < KS * KS; ++tap)
            #pragma unroll
            for (int kk = 0; kk < KSTEPS; ++kk)
                afr[tap * KSTEPS + kk] = *(const short8*)&wr[
                    ((size_t)tap * COUTP + cob + lanelo) * CINP +
                    ck * CHUNK + kk * 32 + laneq * 8];

        // ---- MFMA: taps x ksteps x n-tiles ----
        for (int tap = 0; tap < KS * KS; ++tap) {
            int ky = tap / KS, kx = tap - ky * KS;
            #pragma unroll
            for (int kk = 0; kk < KSTEPS; ++kk) {
                #pragma unroll
                for (int n = 0; n < N_TILES; ++n) {
                    int rr = pg_row0 + (n >> 1) + ky;
                    int px = (n & 1) * 16 + lanelo + (4 - PADK) + kx;
                    const short8 bf = *(const short8*)&lds[
                        (rr * RW + px) * STRIDE + kk * 32 + laneq * 8];
                    acc[n] = __builtin_amdgcn_mfma_f32_16x16x32_bf16(
                        afr[tap * KSTEPS + kk], bf, acc[n], 0, 0, 0);
                }
            }
        }
        __syncthreads();
    }

    // ---- epilogue ----
    #pragma unroll
    for (int n = 0; n < N_TILES; ++n) {
        int x = tx0 + (n & 1) * 16 + lanelo;
        int y = ty0 + pg_row0 + (n >> 1);
        #pragma unroll
        for (int j = 0; j < 4; ++j) {
            int co = cob + laneq * 4 + j;
            float v = acc[n][j];
            if constexpr (OUTBF16) {
                v += bias[co];
                if constexpr (LEAKY) v = v > 0.f ? v : 0.1f * v;
                ((unsigned short*)outp)[((size_t)b * COUTP + co) * HW_ + y * W + x] = f2bf(v);
            } else {
                if (co < coutReal) {
                    v += bias[co];
                    v += (float)flow_up[((size_t)(b * 2) + co) * HW_ + y * W + x];
                    ((float*)outp)[((size_t)b * coutReal + co) * HW_ + y * W + x] = v;
                }
            }
        }
    }
}

// ---------------------------------------------------------------------------
extern "C" void kernel_launch(void* const* d_in, const int* in_sizes, int n_in,
                              void* d_out, int out_size, void* d_ws, size_t ws_size,
                              hipStream_t stream)
{
    const float* feats = (const float*)d_in[0];
    const float* flow  = (const float*)d_in[1];
    const float* up_w  = (const float*)d_in[2];
    const float* w1 = (const float*)d_in[3];
    const float* b1 = (const float*)d_in[4];
    const float* w2 = (const float*)d_in[5];
    const float* b2 = (const float*)d_in[6];
    const float* w3 = (const float*)d_in[7];
    const float* b3 = (const float*)d_in[8];
    const float* w4 = (const float*)d_in[9];
    const float* b4 = (const float*)d_in[10];
    float* out = (float*)d_out;

    char* ws = (char*)d_ws;
    // A: flow_up f64                                    [0,   3.93 MB)
    // B: warped f32 (dies after corr) / h1 bf16 / h3    [3.93, 129.76 MB)
    // C: corr bf16 64ch (dies after conv1) / h2 bf16    [129.76, 161.22 MB)
    // E: repacked weights bf16                          [161.22, 161.58 MB)
    double* flow_up = (double*)ws;
    float* warped = (float*)(ws + 3932160);
    unsigned short* h1 = (unsigned short*)(ws + 3932160);
    unsigned short* h3 = (unsigned short*)(ws + 3932160 + 62914560);
    unsigned short* corrb = (unsigned short*)(ws + 129761280);
    unsigned short* h2 = corrb;
    unsigned short* wr = (unsigned short*)(ws + 161218560);
    unsigned short* wr1 = wr;
    unsigned short* wr2 = wr + 73728;
    unsigned short* wr3 = wr + 147456;
    unsigned short* wr4 = wr + 165888;

    repack_w_kernel<<<699, 256, 0, stream>>>(w1, w2, w3, w4, wr);
    upflow_kernel<<<(B * 2 * HW_ + 255) / 256, 256, 0, stream>>>(flow, up_w, flow_up);
    warp_kernel<<<(B * HW_) / 256, 256, 0, stream>>>(feats, flow_up, warped);
    corr_kernel<<<960, 256, 0, stream>>>(feats, warped, corrb);

    // conv1: cin 64(pad49), cout 128 -> grid.y=2
    conv_mfma_kernel<64, 64, 128, 4, 8, 3, true, false, true>
        <<<dim3(1920, 2), 256, 0, stream>>>(corrb, wr1, b1, h1, nullptr, 128);
    // conv2: cin 128, cout 64
    conv_mfma_kernel<128, 64, 64, 4, 8, 3, true, false, true>
        <<<dim3(1920, 1), 256, 0, stream>>>(h1, wr2, b2, h2, nullptr, 64);
    // conv3: cin 64, cout 32 (2 co-tiles x 2 px-groups)
    conv_mfma_kernel<64, 64, 32, 2, 4, 3, true, false, true>
        <<<dim3(1920, 1), 256, 0, stream>>>(h2, wr3, b3, h3, nullptr, 32);
    // conv4: cin 32, cout 2 (padded 16), 5x5, + bias + flow_up, fp32 out
    conv_mfma_kernel<32, 32, 16, 1, 8, 5, false, true, false>
        <<<dim3(480, 1), 256, 0, stream>>>(h3, wr4, b4, out, flow_up, 2);
}

// Round 3
// 933.426 us; speedup vs baseline: 3.4221x; 1.0852x over previous
//
#include <hip/hip_runtime.h>

typedef __attribute__((ext_vector_type(8))) short short8;
typedef __attribute__((ext_vector_type(4))) float f32x4;
typedef _Float16 half2f __attribute__((ext_vector_type(2)));
typedef unsigned int uint;

constexpr int B = 4, C = 128, H = 192, W = 320;
constexpr int HW_ = H * W;

__device__ __forceinline__ unsigned short f2bf(float x) {
    uint u = __float_as_uint(x);
    u += 0x7fffu + ((u >> 16) & 1u);
    return (unsigned short)(u >> 16);
}
__device__ __forceinline__ uint pack2bf(float a, float b) {
    return (uint)f2bf(a) | ((uint)f2bf(b) << 16);
}
__device__ __forceinline__ float dot2f(uint w, half2f f, float c) {
    half2f wv = __builtin_bit_cast(half2f, w);
#if __has_builtin(__builtin_amdgcn_fdot2)
    return __builtin_amdgcn_fdot2(wv, f, c, false);
#else
    return c + (float)wv.x * (float)f.x + (float)wv.y * (float)f.y;
#endif
}

// ---------------------------------------------------------------------------
// 1) up_flow in fp64 (feeds floor()/mask decisions downstream)
// ---------------------------------------------------------------------------
__global__ __launch_bounds__(256) void upflow_kernel(
    const float* __restrict__ flow, const float* __restrict__ up_w,
    double* __restrict__ flow_up)
{
#pragma clang fp contract(off)
    int idx = blockIdx.x * 256 + threadIdx.x;
    if (idx >= B * 2 * HW_) return;
    int x = idx % W;
    int y = (idx / W) % H;
    int c = (idx / HW_) % 2;
    int b = idx / (2 * HW_);
    double acc = 0.0;
    #pragma unroll
    for (int ky = 0; ky < 4; ++ky) {
        int p = y + ky - 2;
        if (p < 0 || (p & 1) || (p >> 1) >= 96) continue;
        #pragma unroll
        for (int kx = 0; kx < 4; ++kx) {
            int q = x + kx - 2;
            if (q < 0 || (q & 1) || (q >> 1) >= 160) continue;
            double fv = (double)flow[((b * 2 + c) * 96 + (p >> 1)) * 160 + (q >> 1)];
            double wv = (double)up_w[c * 16 + (3 - ky) * 4 + (3 - kx)];
            double prod = fv * wv;
            acc = acc + prod;
        }
    }
    flow_up[idx] = acc;
}

// ---------------------------------------------------------------------------
// 2) warp: bilinear + oob mask, fp64 coords; OUTPUT = f16-pair dwords
//    wp layout: [b][c/2][H][W] uint (lo half = even ch, hi = odd ch)
// ---------------------------------------------------------------------------
__global__ __launch_bounds__(256) void warp_kernel(
    const float* __restrict__ feats, const double* __restrict__ flow_up,
    uint* __restrict__ wp)
{
#pragma clang fp contract(off)
    int idx = blockIdx.x * 256 + threadIdx.x;   // over B*H*W
    int x = idx % W;
    int y = (idx / W) % H;
    int b = idx / HW_;

    double f0 = flow_up[(size_t)(b * 2 + 0) * HW_ + y * W + x];
    double f1 = flow_up[(size_t)(b * 2 + 1) * HW_ + y * W + x];

    double stepx = 2.0 / (double)(W - 1);
    double stepy = 2.0 / (double)(H - 1);
    double gx = (x == W - 1) ? 1.0 : ((double)x * stepx + (-1.0));
    double gy = (y == H - 1) ? 1.0 : ((double)y * stepy + (-1.0));
    double cxs = 2.0 * 2.5 / (double)(W - 1);
    double cys = 2.0 * 2.5 / (double)(H - 1);
    double sx = gx + f0 * cxs;
    double sy = gy + f1 * cys;
    double px = (sx + 1.0) * 0.5 * (double)(W - 1);
    double py = (sy + 1.0) * 0.5 * (double)(H - 1);

    double pxc = px < 0.0 ? 0.0 : (px > (double)(W - 1) ? (double)(W - 1) : px);
    double pyc = py < 0.0 ? 0.0 : (py > (double)(H - 1) ? (double)(H - 1) : py);
    double x0 = floor(pxc), y0 = floor(pyc);
    double tx = pxc - x0, ty = pyc - y0;
    int x0i = (int)x0, y0i = (int)y0;
    int x1i = min(x0i + 1, W - 1), y1i = min(y0i + 1, H - 1);

    double fx0 = floor(px), fy0 = floor(py);
    double mtx = px - fx0, mty = py - fy0;
    double w00 = (1.0 - mtx) * (1.0 - mty);
    double w01 = mtx * (1.0 - mty);
    double w10 = (1.0 - mtx) * mty;
    double w11 = mtx * mty;
    double m = 0.0;
    double xi, yi;
    xi = fx0;       yi = fy0;
    if (xi >= 0.0 && xi <= (double)(W - 1) && yi >= 0.0 && yi <= (double)(H - 1)) m = m + w00;
    xi = fx0 + 1.0; yi = fy0;
    if (xi >= 0.0 && xi <= (double)(W - 1) && yi >= 0.0 && yi <= (double)(H - 1)) m = m + w01;
    xi = fx0;       yi = fy0 + 1.0;
    if (xi >= 0.0 && xi <= (double)(W - 1) && yi >= 0.0 && yi <= (double)(H - 1)) m = m + w10;
    xi = fx0 + 1.0; yi = fy0 + 1.0;
    if (xi >= 0.0 && xi <= (double)(W - 1) && yi >= 0.0 && yi <= (double)(H - 1)) m = m + w11;
    float mask = (m >= 1.0) ? 1.0f : 0.0f;

    float a00 = (float)((1.0 - tx) * (1.0 - ty)) * mask;
    float a01 = (float)(tx * (1.0 - ty)) * mask;
    float a10 = (float)((1.0 - tx) * ty) * mask;
    float a11 = (float)(tx * ty) * mask;

    int o00 = y0i * W + x0i;
    int o01 = y0i * W + x1i;
    int o10 = y1i * W + x0i;
    int o11 = y1i * W + x1i;
    const float* img = feats + (size_t)(b * 2 + 1) * C * HW_;
    uint* dst = wp + (size_t)b * 64 * HW_ + y * W + x;
    for (int c2 = 0; c2 < 64; ++c2) {
        const float* p0 = img + (size_t)(2 * c2) * HW_;
        const float* p1 = p0 + HW_;
        float lo = a00 * p0[o00] + a01 * p0[o01] + a10 * p0[o10] + a11 * p0[o11];
        float hi = a00 * p1[o00] + a01 * p1[o01] + a10 * p1[o10] + a11 * p1[o11];
        half2f h = {(_Float16)lo, (_Float16)hi};
        dst[(size_t)c2 * HW_] = __builtin_bit_cast(uint, h);
    }
}

// ---------------------------------------------------------------------------
// 3) weight repack:  w -> [tap][coP][cinP] bf16, zero-padded
//    wr1 [9][128][64] | wr2 [9][64][128] | wr3 [9][32][64] | wr4 [25][16][32]
// ---------------------------------------------------------------------------
__global__ __launch_bounds__(256) void repack_w_kernel(
    const float* __restrict__ w1, const float* __restrict__ w2,
    const float* __restrict__ w3, const float* __restrict__ w4,
    unsigned short* __restrict__ wr)
{
    int idx = blockIdx.x * 256 + threadIdx.x;
    if (idx >= 178688) return;
    float v = 0.f;
    if (idx < 73728) {
        int tap = idx / 8192, r = idx % 8192, co = r / 64, ci = r % 64;
        if (ci < 49) v = w1[(co * 49 + ci) * 9 + tap];
    } else if (idx < 147456) {
        int i2 = idx - 73728;
        int tap = i2 / 8192, r = i2 % 8192, co = r / 128, ci = r % 128;
        v = w2[(co * 128 + ci) * 9 + tap];
    } else if (idx < 165888) {
        int i3 = idx - 147456;
        int tap = i3 / 2048, r = i3 % 2048, co = r / 64, ci = r % 64;
        v = w3[(co * 64 + ci) * 9 + tap];
    } else {
        int i4 = idx - 165888;
        int tap = i4 / 512, r = i4 % 512, co = r / 32, ci = r % 32;
        if (co < 2) v = w4[(co * 32 + ci) * 25 + tap];
    }
    wr[idx] = f2bf(v);
}

// ---------------------------------------------------------------------------
// 4) correlation v2: f16 dot2, 16x8 px tile, channel-split across 2 halves.
//    in: wp f16-pairs; out: corrb bf16-pair dwords [b][32][H][W] (planes 25..31 = 0)
// ---------------------------------------------------------------------------
__global__ __launch_bounds__(256) void corr_kernel(
    const float* __restrict__ feats, const uint* __restrict__ wp,
    uint* __restrict__ corrb)
{
    __shared__ uint smem[6272];                 // tile 16*322=5152 | red 128*49=6272
    int t = blockIdx.x;
    int xt = t % 20, yt = (t / 20) % 24, b = t / 480;
    int tx0 = xt * 16, ty0 = yt * 8;
    int tid = threadIdx.x;
    int px = tid & 127, chalf = tid >> 7;
    int xl = px & 15, yl = px >> 4;
    int x = tx0 + xl, y = ty0 + yl;

    float acc[49];
    #pragma unroll
    for (int k = 0; k < 49; ++k) acc[k] = 0.f;

    const float* f1b = feats + (size_t)(b * 2) * C * HW_ + y * W + x;
    const uint* wpb = wp + (size_t)b * 64 * HW_;

    for (int ck = 0; ck < 4; ++ck) {
        half2f f1h[8];
        #pragma unroll
        for (int pp = 0; pp < 8; ++pp) {
            int pair = chalf * 32 + ck * 8 + pp;
            float lo = f1b[(size_t)(2 * pair) * HW_];
            float hi = f1b[(size_t)(2 * pair + 1) * HW_];
            f1h[pp] = half2f{(_Float16)lo, (_Float16)hi};
        }
        for (int s = tid; s < 16 * 322; s += 256) {
            int pp_s = s / 322, idx = s - pp_s * 322;
            int r = idx / 23, c = idx - r * 23;
            uint v = 0;
            if (c < 22) {
                int gy = ty0 + r - 3, gx = tx0 + c - 3;
                int pair = (pp_s >> 3) * 32 + ck * 8 + (pp_s & 7);
                if (gy >= 0 && gy < H && gx >= 0 && gx < W)
                    v = wpb[(size_t)pair * HW_ + gy * W + gx];
            }
            smem[s] = v;
        }
        __syncthreads();
        #pragma unroll
        for (int pp = 0; pp < 8; ++pp) {
            const uint* base = smem + (chalf * 8 + pp) * 322 + yl * 23 + xl;
            #pragma unroll
            for (int di = 0; di < 7; ++di) {
                const uint* rp = base + di * 23;
                #pragma unroll
                for (int dj = 0; dj < 7; ++dj)
                    acc[di * 7 + dj] = dot2f(rp[dj], f1h[pp], acc[di * 7 + dj]);
            }
        }
        __syncthreads();
    }
    // cross-half reduce + epilogue
    if (chalf) {
        #pragma unroll
        for (int k = 0; k < 49; ++k) smem[px * 49 + k] = __float_as_uint(acc[k]);
    }
    __syncthreads();
    if (!chalf) {
        #pragma unroll
        for (int k = 0; k < 49; ++k) acc[k] += __uint_as_float(smem[px * 49 + k]);
        uint* outp = corrb + (size_t)b * 32 * HW_ + y * W + x;
        #pragma unroll
        for (int k2 = 0; k2 < 24; ++k2) {
            float v0 = acc[2 * k2];     v0 = v0 > 0.f ? v0 : 0.1f * v0;
            float v1 = acc[2 * k2 + 1]; v1 = v1 > 0.f ? v1 : 0.1f * v1;
            outp[(size_t)k2 * HW_] = pack2bf(v0 * (1.0f / 128.0f), v1 * (1.0f / 128.0f));
        }
        float v0 = acc[48]; v0 = v0 > 0.f ? v0 : 0.1f * v0;
        outp[(size_t)24 * HW_] = (uint)f2bf(v0 * (1.0f / 128.0f));
        #pragma unroll
        for (int k2 = 25; k2 < 32; ++k2) outp[(size_t)k2 * HW_] = 0;
    }
}

// ---------------------------------------------------------------------------
// 5) implicit-GEMM MFMA conv. Inputs as bf16-pair dword planes [b][ci/2][H][W].
//    LDS [px][chunk-ch] halfs, dword-stride S2=20 (80 B, 16B-aligned rows).
//    CHUNK=32 -> 19.2/25.6 KB LDS for occupancy.
// ---------------------------------------------------------------------------
template<int CINP, int COUTP, int M_TILES, int N_TILES, int KS,
         bool LEAKY, bool ADDFLOW, bool OUTBF16, int MINW>
__global__ __launch_bounds__(256, MINW) void conv_mfma_kernel(
    const uint* __restrict__ in, const unsigned short* __restrict__ wr,
    const float* __restrict__ bias, void* __restrict__ outp,
    const double* __restrict__ flow_up, int coutReal)
{
    constexpr int CHUNK = 32;
    constexpr int PADK = KS / 2;
    constexpr int PX_GROUPS = 4 / M_TILES;
    constexpr int TH = PX_GROUPS * (N_TILES / 2);
    constexpr int RH = TH + KS - 1;
    constexpr int RW = 40;
    constexpr int S2 = 20;
    constexpr int CHUNKS = CINP / CHUNK;
    __shared__ uint lds32[RH * RW * S2];

    int tid = threadIdx.x;
    int lanelo = tid & 15, laneq = (tid >> 4) & 3, wave = tid >> 6;
    int m_idx = wave % M_TILES, pgroup = wave / M_TILES;
    int pg_row0 = pgroup * (N_TILES / 2);

    int bx = blockIdx.x;
    int xt = bx % 10;
    int yt = (bx / 10) % (H / TH);
    int b = bx / (10 * (H / TH));
    int tx0 = xt * 32, ty0 = yt * TH;
    int cob = blockIdx.y * (M_TILES * 16) + m_idx * 16;

    f32x4 acc[N_TILES];
    #pragma unroll
    for (int n = 0; n < N_TILES; ++n) acc[n] = f32x4{0.f, 0.f, 0.f, 0.f};

    const uint* inb = in + (size_t)b * (CINP / 2) * HW_;

    for (int ck = 0; ck < CHUNKS; ++ck) {
        constexpr int UNITS = RH * (CHUNK / 2) * 10;
        for (int s = tid; s < UNITS; s += 256) {
            int q = s % 10;
            int pp = (s / 10) % (CHUNK / 2);
            int r = s / (10 * (CHUNK / 2));
            int gy = ty0 - PADK + r;
            int gx0 = tx0 - 4 + q * 4;
            uint4 v = {0, 0, 0, 0};
            if (gy >= 0 && gy < H && gx0 >= 0 && gx0 < W)
                v = *(const uint4*)&inb[(size_t)(ck * (CHUNK / 2) + pp) * HW_ + gy * W + gx0];
            int pbase = (r * RW + q * 4) * S2 + pp;
            lds32[pbase] = v.x;
            lds32[pbase + S2] = v.y;
            lds32[pbase + 2 * S2] = v.z;
            lds32[pbase + 3 * S2] = v.w;
        }
        __syncthreads();

        short8 afr[KS * KS];
        #pragma unroll
        for (int tap = 0; tap < KS * KS; ++tap)
            afr[tap] = *(const short8*)&wr[
                ((size_t)tap * COUTP + cob + lanelo) * CINP + ck * CHUNK + laneq * 8];

        for (int tap = 0; tap < KS * KS; ++tap) {
            int ky = tap / KS, kx = tap - ky * KS;
            #pragma unroll
            for (int n = 0; n < N_TILES; ++n) {
                int rr = pg_row0 + (n >> 1) + ky;
                int pxi = (n & 1) * 16 + lanelo + (4 - PADK) + kx;
                const short8 bf = *(const short8*)&lds32[(rr * RW + pxi) * S2 + laneq * 4];
                acc[n] = __builtin_amdgcn_mfma_f32_16x16x32_bf16(afr[tap], bf, acc[n], 0, 0, 0);
            }
        }
        __syncthreads();
    }

    // ---- epilogue ----
    #pragma unroll
    for (int n = 0; n < N_TILES; ++n) {
        int x = tx0 + (n & 1) * 16 + lanelo;
        int y = ty0 + pg_row0 + (n >> 1);
        if constexpr (OUTBF16) {
            float v[4];
            #pragma unroll
            for (int j = 0; j < 4; ++j) {
                v[j] = acc[n][j] + bias[cob + laneq * 4 + j];
                if constexpr (LEAKY) v[j] = v[j] > 0.f ? v[j] : 0.1f * v[j];
            }
            uint* op = (uint*)outp + ((size_t)b * (COUTP / 2) + ((cob + laneq * 4) >> 1)) * HW_ + y * W + x;
            op[0] = pack2bf(v[0], v[1]);
            op[HW_] = pack2bf(v[2], v[3]);
        } else {
            #pragma unroll
            for (int j = 0; j < 4; ++j) {
                int co = cob + laneq * 4 + j;
                if (co < coutReal) {
                    float v = acc[n][j] + bias[co];
                    v += (float)flow_up[((size_t)(b * 2) + co) * HW_ + y * W + x];
                    ((float*)outp)[((size_t)b * coutReal + co) * HW_ + y * W + x] = v;
                }
            }
        }
    }
}

// ---------------------------------------------------------------------------
extern "C" void kernel_launch(void* const* d_in, const int* in_sizes, int n_in,
                              void* d_out, int out_size, void* d_ws, size_t ws_size,
                              hipStream_t stream)
{
    const float* feats = (const float*)d_in[0];
    const float* flow  = (const float*)d_in[1];
    const float* up_w  = (const float*)d_in[2];
    const float* w1 = (const float*)d_in[3];
    const float* b1 = (const float*)d_in[4];
    const float* w2 = (const float*)d_in[5];
    const float* b2 = (const float*)d_in[6];
    const float* w3 = (const float*)d_in[7];
    const float* b3 = (const float*)d_in[8];
    const float* w4 = (const float*)d_in[9];
    const float* b4 = (const float*)d_in[10];
    float* out = (float*)d_out;

    char* ws = (char*)d_ws;
    // 0        : flow_up f64                       3,932,160 B
    // 3932160  : warped f16-pairs / h1 bf16-pairs  62,914,560 B
    // 66846720 : corrb / h2 bf16-pairs             31,457,280 B
    // 98304000 : h3 bf16-pairs                     15,728,640 B
    // 114032640: wr bf16 weights                   357,376 B
    double* flow_up = (double*)ws;
    uint* wp    = (uint*)(ws + 3932160);
    uint* h1    = (uint*)(ws + 3932160);
    uint* corrb = (uint*)(ws + 66846720);
    uint* h2    = corrb;
    uint* h3    = (uint*)(ws + 98304000);
    unsigned short* wr = (unsigned short*)(ws + 114032640);
    unsigned short* wr1 = wr;
    unsigned short* wr2 = wr + 73728;
    unsigned short* wr3 = wr + 147456;
    unsigned short* wr4 = wr + 165888;

    repack_w_kernel<<<699, 256, 0, stream>>>(w1, w2, w3, w4, wr);
    upflow_kernel<<<(B * 2 * HW_ + 255) / 256, 256, 0, stream>>>(flow, up_w, flow_up);
    warp_kernel<<<(B * HW_) / 256, 256, 0, stream>>>(feats, flow_up, wp);
    corr_kernel<<<1920, 256, 0, stream>>>(feats, wp, corrb);

    // conv1: cin 64(pad49), cout 128
    conv_mfma_kernel<64, 128, 4, 8, 3, true, false, true, 4>
        <<<dim3(1920, 2), 256, 0, stream>>>(corrb, wr1, b1, h1, nullptr, 128);
    // conv2: cin 128, cout 64
    conv_mfma_kernel<128, 64, 4, 8, 3, true, false, true, 4>
        <<<dim3(1920, 1), 256, 0, stream>>>(h1, wr2, b2, h2, nullptr, 64);
    // conv3: cin 64, cout 32
    conv_mfma_kernel<64, 32, 2, 4, 3, true, false, true, 4>
        <<<dim3(1920, 1), 256, 0, stream>>>(h2, wr3, b3, h3, nullptr, 32);
    // conv4: cin 32, cout 2 (pad 16), 5x5, fp32 out + bias + flow_up
    conv_mfma_kernel<32, 16, 1, 2, 5, false, true, false, 2>
        <<<dim3(1920, 1), 256, 0, stream>>>(h3, wr4, b4, out, flow_up, 2);
}

// Round 4
// 788.055 us; speedup vs baseline: 4.0533x; 1.1845x over previous
//
#include <hip/hip_runtime.h>

typedef __attribute__((ext_vector_type(8))) short short8;
typedef __attribute__((ext_vector_type(4))) float f32x4;
typedef __attribute__((ext_vector_type(16))) float f32x16;
typedef unsigned int uint;

constexpr int B = 4, C = 128, H = 192, W = 320;
constexpr int HW_ = H * W;

__device__ __forceinline__ unsigned short f2bf(float x) {
    uint u = __float_as_uint(x);
    u += 0x7fffu + ((u >> 16) & 1u);
    return (unsigned short)(u >> 16);
}
__device__ __forceinline__ uint pack2bf(float a, float b) {
    return (uint)f2bf(a) | ((uint)f2bf(b) << 16);
}

// ---------------------------------------------------------------------------
// 1) up_flow in fp64 (feeds floor()/mask decisions downstream)
// ---------------------------------------------------------------------------
__global__ __launch_bounds__(256) void upflow_kernel(
    const float* __restrict__ flow, const float* __restrict__ up_w,
    double* __restrict__ flow_up)
{
#pragma clang fp contract(off)
    int idx = blockIdx.x * 256 + threadIdx.x;
    if (idx >= B * 2 * HW_) return;
    int x = idx % W;
    int y = (idx / W) % H;
    int c = (idx / HW_) % 2;
    int b = idx / (2 * HW_);
    double acc = 0.0;
    #pragma unroll
    for (int ky = 0; ky < 4; ++ky) {
        int p = y + ky - 2;
        if (p < 0 || (p & 1) || (p >> 1) >= 96) continue;
        #pragma unroll
        for (int kx = 0; kx < 4; ++kx) {
            int q = x + kx - 2;
            if (q < 0 || (q & 1) || (q >> 1) >= 160) continue;
            double fv = (double)flow[((b * 2 + c) * 96 + (p >> 1)) * 160 + (q >> 1)];
            double wv = (double)up_w[c * 16 + (3 - ky) * 4 + (3 - kx)];
            double prod = fv * wv;
            acc = acc + prod;
        }
    }
    flow_up[idx] = acc;
}

// ---------------------------------------------------------------------------
// 2) warp: bilinear + oob mask, fp64 coords; OUTPUT = bf16-pair dwords
//    wp layout: [b][c/2][H][W] uint (lo half = even ch, hi = odd ch)
// ---------------------------------------------------------------------------
__global__ __launch_bounds__(256) void warp_kernel(
    const float* __restrict__ feats, const double* __restrict__ flow_up,
    uint* __restrict__ wp)
{
#pragma clang fp contract(off)
    int idx = blockIdx.x * 256 + threadIdx.x;   // over B*H*W
    int x = idx % W;
    int y = (idx / W) % H;
    int b = idx / HW_;

    double f0 = flow_up[(size_t)(b * 2 + 0) * HW_ + y * W + x];
    double f1 = flow_up[(size_t)(b * 2 + 1) * HW_ + y * W + x];

    double stepx = 2.0 / (double)(W - 1);
    double stepy = 2.0 / (double)(H - 1);
    double gx = (x == W - 1) ? 1.0 : ((double)x * stepx + (-1.0));
    double gy = (y == H - 1) ? 1.0 : ((double)y * stepy + (-1.0));
    double cxs = 2.0 * 2.5 / (double)(W - 1);
    double cys = 2.0 * 2.5 / (double)(H - 1);
    double sx = gx + f0 * cxs;
    double sy = gy + f1 * cys;
    double px = (sx + 1.0) * 0.5 * (double)(W - 1);
    double py = (sy + 1.0) * 0.5 * (double)(H - 1);

    double pxc = px < 0.0 ? 0.0 : (px > (double)(W - 1) ? (double)(W - 1) : px);
    double pyc = py < 0.0 ? 0.0 : (py > (double)(H - 1) ? (double)(H - 1) : py);
    double x0 = floor(pxc), y0 = floor(pyc);
    double tx = pxc - x0, ty = pyc - y0;
    int x0i = (int)x0, y0i = (int)y0;
    int x1i = min(x0i + 1, W - 1), y1i = min(y0i + 1, H - 1);

    double fx0 = floor(px), fy0 = floor(py);
    double mtx = px - fx0, mty = py - fy0;
    double w00 = (1.0 - mtx) * (1.0 - mty);
    double w01 = mtx * (1.0 - mty);
    double w10 = (1.0 - mtx) * mty;
    double w11 = mtx * mty;
    double m = 0.0;
    double xi, yi;
    xi = fx0;       yi = fy0;
    if (xi >= 0.0 && xi <= (double)(W - 1) && yi >= 0.0 && yi <= (double)(H - 1)) m = m + w00;
    xi = fx0 + 1.0; yi = fy0;
    if (xi >= 0.0 && xi <= (double)(W - 1) && yi >= 0.0 && yi <= (double)(H - 1)) m = m + w01;
    xi = fx0;       yi = fy0 + 1.0;
    if (xi >= 0.0 && xi <= (double)(W - 1) && yi >= 0.0 && yi <= (double)(H - 1)) m = m + w10;
    xi = fx0 + 1.0; yi = fy0 + 1.0;
    if (xi >= 0.0 && xi <= (double)(W - 1) && yi >= 0.0 && yi <= (double)(H - 1)) m = m + w11;
    float mask = (m >= 1.0) ? 1.0f : 0.0f;

    float a00 = (float)((1.0 - tx) * (1.0 - ty)) * mask;
    float a01 = (float)(tx * (1.0 - ty)) * mask;
    float a10 = (float)((1.0 - tx) * ty) * mask;
    float a11 = (float)(tx * ty) * mask;

    int o00 = y0i * W + x0i;
    int o01 = y0i * W + x1i;
    int o10 = y1i * W + x0i;
    int o11 = y1i * W + x1i;
    const float* img = feats + (size_t)(b * 2 + 1) * C * HW_;
    uint* dst = wp + (size_t)b * 64 * HW_ + y * W + x;
    for (int c2 = 0; c2 < 64; ++c2) {
        const float* p0 = img + (size_t)(2 * c2) * HW_;
        const float* p1 = p0 + HW_;
        float lo = a00 * p0[o00] + a01 * p0[o01] + a10 * p0[o10] + a11 * p0[o11];
        float hi = a00 * p1[o00] + a01 * p1[o01] + a10 * p1[o10] + a11 * p1[o11];
        dst[(size_t)c2 * HW_] = pack2bf(lo, hi);
    }
}

// ---------------------------------------------------------------------------
// 3) weight repack:  w -> [tap][coP][cinP] bf16, zero-padded
//    wr1 [9][128][64] | wr2 [9][64][128] | wr3 [9][32][64] | wr4 [25][16][32]
// ---------------------------------------------------------------------------
__global__ __launch_bounds__(256) void repack_w_kernel(
    const float* __restrict__ w1, const float* __restrict__ w2,
    const float* __restrict__ w3, const float* __restrict__ w4,
    unsigned short* __restrict__ wr)
{
    int idx = blockIdx.x * 256 + threadIdx.x;
    if (idx >= 178688) return;
    float v = 0.f;
    if (idx < 73728) {
        int tap = idx / 8192, r = idx % 8192, co = r / 64, ci = r % 64;
        if (ci < 49) v = w1[(co * 49 + ci) * 9 + tap];
    } else if (idx < 147456) {
        int i2 = idx - 73728;
        int tap = i2 / 8192, r = i2 % 8192, co = r / 128, ci = r % 128;
        v = w2[(co * 128 + ci) * 9 + tap];
    } else if (idx < 165888) {
        int i3 = idx - 147456;
        int tap = i3 / 2048, r = i3 % 2048, co = r / 64, ci = r % 64;
        v = w3[(co * 64 + ci) * 9 + tap];
    } else {
        int i4 = idx - 165888;
        int tap = i4 / 512, r = i4 % 512, co = r / 32, ci = r % 32;
        if (co < 2) v = w4[(co * 32 + ci) * 25 + tap];
    }
    wr[idx] = f2bf(v);
}

// ---------------------------------------------------------------------------
// 4) correlation via MFMA: banded QK^T over 7x22 window flattened to 10 K-tiles.
//    Block: 32 px x 2 rows; 4 waves = 2 xhalf x 2 row. K/Q LDS [px][40 halfs].
// ---------------------------------------------------------------------------
__global__ __launch_bounds__(256, 4) void corr_kernel(
    const float* __restrict__ feats, const uint* __restrict__ wp,
    uint* __restrict__ corrb)
{
    __shared__ unsigned short lds[(320 + 64) * 40];   // K: 8x40 px | Q: 64 px
    float* stage = (float*)lds;                        // 49*64 f32 epilogue stage

    int t = blockIdx.x;
    int xt = t % 10, yg = (t / 10) % 96, b = t / 960;
    int x0 = xt * 32, y0 = yg * 2;
    int tid = threadIdx.x;
    int lane = tid & 63, wave = tid >> 6;
    int lanelo = lane & 15, laneq = (lane >> 4) & 3;
    int h = wave & 1, yr = wave >> 1;

    // per-lane window-tile addresses (halfs), hoisted out of the ck loop
    int baddr[10], di_t[10], c_t[10];
    #pragma unroll
    for (int tt = 0; tt < 10; ++tt) {
        int p = tt * 16 + lanelo;
        int di = p / 22, cc = p - di * 22;
        di_t[tt] = di; c_t[tt] = cc;
        int addr = ((yr + di) * 40 + h * 16 + cc + 1) * 40 + laneq * 8;
        baddr[tt] = (di > 6) ? 0 : addr;
    }
    int qaddr = (320 + yr * 32 + h * 16 + lanelo) * 40 + laneq * 8;

    f32x4 acc[10];
    #pragma unroll
    for (int tt = 0; tt < 10; ++tt) acc[tt] = f32x4{0.f, 0.f, 0.f, 0.f};

    const uint* wpb = wp + (size_t)b * 64 * HW_;
    const float* f1b = feats + (size_t)(b * 2) * C * HW_;

    for (int ck = 0; ck < 4; ++ck) {
        if (ck) __syncthreads();
        // stage K chunk: 8 rows x 10 quads x 16 pairs
        #pragma unroll
        for (int i = 0; i < 5; ++i) {
            int u = tid + i * 256;
            int q = u % 10, pp = (u / 10) & 15, r = u / 160;
            int gy = y0 - 3 + r, gx0 = x0 - 4 + 4 * q;
            uint4 v = {0, 0, 0, 0};
            if (gy >= 0 && gy < H && gx0 >= 0 && gx0 < W)
                v = *(const uint4*)&wpb[(size_t)(ck * 16 + pp) * HW_ + gy * W + gx0];
            int pxb = (r * 40 + 4 * q) * 40 + 2 * pp;
            *(uint*)&lds[pxb]       = v.x;
            *(uint*)&lds[pxb + 40]  = v.y;
            *(uint*)&lds[pxb + 80]  = v.z;
            *(uint*)&lds[pxb + 120] = v.w;
        }
        // stage Q chunk: 64 px x 16 pairs, fp32 -> bf16
        #pragma unroll
        for (int i = 0; i < 4; ++i) {
            int u = tid + i * 256;
            int px = u & 63, pp = u >> 6;
            int gx = x0 + (px & 31), gy = y0 + (px >> 5);
            const float* p0 = f1b + (size_t)(ck * 32 + 2 * pp) * HW_ + gy * W + gx;
            *(uint*)&lds[(320 + px) * 40 + 2 * pp] = pack2bf(p0[0], p0[HW_]);
        }
        __syncthreads();
        const short8 qf = *(const short8*)&lds[qaddr];
        #pragma unroll
        for (int tt = 0; tt < 10; ++tt) {
            const short8 kf = *(const short8*)&lds[baddr[tt]];
            acc[tt] = __builtin_amdgcn_mfma_f32_16x16x32_bf16(qf, kf, acc[tt], 0, 0, 0);
        }
    }
    __syncthreads();
    // scatter the valid band entries: S[i, p] -> stage[di*7+dj][px]
    #pragma unroll
    for (int tt = 0; tt < 10; ++tt) {
        int di = di_t[tt];
        #pragma unroll
        for (int reg = 0; reg < 4; ++reg) {
            int i = laneq * 4 + reg;
            int dj = c_t[tt] - i;
            if (di <= 6 && dj >= 0 && dj < 7)
                stage[(di * 7 + dj) * 64 + yr * 32 + h * 16 + i] = acc[tt][reg];
        }
    }
    __syncthreads();
    // leaky + /128 + bf16 pair-pack + store
    uint* outp = corrb + (size_t)b * 32 * HW_;
    #pragma unroll
    for (int i = 0; i < 8; ++i) {
        int u = tid + i * 256;
        int px = u & 63, k2 = u >> 6;
        int gx = x0 + (px & 31), gy = y0 + (px >> 5);
        float v0 = (2 * k2 < 49) ? stage[(2 * k2) * 64 + px] : 0.f;
        float v1 = (2 * k2 + 1 < 49) ? stage[(2 * k2 + 1) * 64 + px] : 0.f;
        v0 = v0 > 0.f ? v0 : 0.1f * v0;
        v1 = v1 > 0.f ? v1 : 0.1f * v1;
        outp[(size_t)k2 * HW_ + gy * W + gx] = pack2bf(v0 * (1.f / 128.f), v1 * (1.f / 128.f));
    }
}

// ---------------------------------------------------------------------------
// 5) 3x3 conv, 32x32x16 MFMA, intra-wave co-reuse (each B frag -> MG MFMAs).
//    Wave = MG*32 co x NR rows of 32 px. Block = WCO co-sets x WROWS row-groups.
// ---------------------------------------------------------------------------
template<int CINP, int COUTP, int WCO, int WROWS, int MG, int NR, int MINW>
__global__ __launch_bounds__(256, MINW) void conv3x3_kernel(
    const uint* __restrict__ in, const unsigned short* __restrict__ wr,
    const float* __restrict__ bias, uint* __restrict__ outp)
{
    constexpr int TH = WROWS * NR;
    constexpr int RH = TH + 2;
    constexpr int RW = 40, S2 = 20;
    constexpr int CHUNKS = CINP / 32;
    __shared__ uint lds32[RH * RW * S2];

    int tid = threadIdx.x;
    int lane = tid & 63, wave = tid >> 6;
    int lane5 = lane & 31, kg = lane >> 5;
    int cow = (WCO == 1) ? 0 : (wave & 1);
    int rowg = (WCO == 1) ? wave : (wave >> 1);

    int bx = blockIdx.x;
    int xt = bx % 10;
    int yt = (bx / 10) % (H / TH);
    int b = bx / (10 * (H / TH));
    int tx0 = xt * 32, ty0 = yt * TH;
    int cob = cow * MG * 32;

    f32x16 acc[MG][NR];
    #pragma unroll
    for (int mg = 0; mg < MG; ++mg)
        #pragma unroll
        for (int nr = 0; nr < NR; ++nr)
            #pragma unroll
            for (int j = 0; j < 16; ++j) acc[mg][nr][j] = 0.f;

    const uint* inb = in + (size_t)b * (CINP / 2) * HW_;

    for (int ck = 0; ck < CHUNKS; ++ck) {
        if (ck) __syncthreads();
        constexpr int UNITS = RH * 10 * 16;
        for (int s = tid; s < UNITS; s += 256) {
            int q = s % 10;
            int pp = (s / 10) % 16;
            int r = s / 160;
            int gy = ty0 - 1 + r;
            int gx0 = tx0 - 4 + 4 * q;
            uint4 v = {0, 0, 0, 0};
            if (gy >= 0 && gy < H && gx0 >= 0 && gx0 < W)
                v = *(const uint4*)&inb[(size_t)(ck * 16 + pp) * HW_ + gy * W + gx0];
            int pbase = (r * RW + 4 * q) * S2 + pp;
            lds32[pbase]          = v.x;
            lds32[pbase + S2]     = v.y;
            lds32[pbase + 2 * S2] = v.z;
            lds32[pbase + 3 * S2] = v.w;
        }
        __syncthreads();

        for (int tap = 0; tap < 9; ++tap) {   // dynamic: keeps A-frag regs low
            int ky = tap / 3, kx = tap - ky * 3;
            short8 A[MG][2];
            #pragma unroll
            for (int mg = 0; mg < MG; ++mg)
                #pragma unroll
                for (int ks = 0; ks < 2; ++ks)
                    A[mg][ks] = *(const short8*)&wr[
                        ((size_t)tap * COUTP + cob + mg * 32 + lane5) * CINP +
                        ck * 32 + ks * 16 + kg * 8];
            #pragma unroll
            for (int nr = 0; nr < NR; ++nr) {
                int rr = rowg * NR + nr + ky;
                int col = lane5 + kx + 3;
                #pragma unroll
                for (int ks = 0; ks < 2; ++ks) {
                    const short8 Bf = *(const short8*)&lds32[(rr * RW + col) * S2 + ks * 8 + kg * 4];
                    #pragma unroll
                    for (int mg = 0; mg < MG; ++mg)
                        acc[mg][nr] = __builtin_amdgcn_mfma_f32_32x32x16_bf16(
                            A[mg][ks], Bf, acc[mg][nr], 0, 0, 0);
                }
            }
        }
    }

    // epilogue: C row = (reg&3) + 8*(reg>>2) + 4*kg; reg pairs -> even co pairs
    int xg = tx0 + lane5;
    #pragma unroll
    for (int mg = 0; mg < MG; ++mg)
        #pragma unroll
        for (int nr = 0; nr < NR; ++nr) {
            int ygl = ty0 + rowg * NR + nr;
            #pragma unroll
            for (int j = 0; j < 8; ++j) {
                int com = ((2 * j) & 3) + 8 * (j >> 1) + 4 * kg;
                int co = cob + mg * 32 + com;
                float v0 = acc[mg][nr][2 * j] + bias[co];
                float v1 = acc[mg][nr][2 * j + 1] + bias[co + 1];
                v0 = v0 > 0.f ? v0 : 0.1f * v0;
                v1 = v1 > 0.f ? v1 : 0.1f * v1;
                outp[((size_t)b * (COUTP / 2) + (co >> 1)) * HW_ + ygl * W + xg] =
                    pack2bf(v0, v1);
            }
        }
}

// ---------------------------------------------------------------------------
// 6) conv4 (5x5, cout 2 padded to 16, +bias +flow_up, fp32 out) — 16x16x32 MFMA
// ---------------------------------------------------------------------------
template<int CINP, int COUTP, int M_TILES, int N_TILES, int KS, int MINW>
__global__ __launch_bounds__(256, MINW) void conv_mfma_kernel(
    const uint* __restrict__ in, const unsigned short* __restrict__ wr,
    const float* __restrict__ bias, float* __restrict__ outp,
    const double* __restrict__ flow_up, int coutReal)
{
    constexpr int CHUNK = 32;
    constexpr int PADK = KS / 2;
    constexpr int PX_GROUPS = 4 / M_TILES;
    constexpr int TH = PX_GROUPS * (N_TILES / 2);
    constexpr int RH = TH + KS - 1;
    constexpr int RW = 40;
    constexpr int S2 = 20;
    constexpr int CHUNKS = CINP / CHUNK;
    __shared__ uint lds32[RH * RW * S2];

    int tid = threadIdx.x;
    int lanelo = tid & 15, laneq = (tid >> 4) & 3, wave = tid >> 6;
    int m_idx = wave % M_TILES, pgroup = wave / M_TILES;
    int pg_row0 = pgroup * (N_TILES / 2);

    int bx = blockIdx.x;
    int xt = bx % 10;
    int yt = (bx / 10) % (H / TH);
    int b = bx / (10 * (H / TH));
    int tx0 = xt * 32, ty0 = yt * TH;
    int cob = m_idx * 16;

    f32x4 acc[N_TILES];
    #pragma unroll
    for (int n = 0; n < N_TILES; ++n) acc[n] = f32x4{0.f, 0.f, 0.f, 0.f};

    const uint* inb = in + (size_t)b * (CINP / 2) * HW_;

    for (int ck = 0; ck < CHUNKS; ++ck) {
        constexpr int UNITS = RH * (CHUNK / 2) * 10;
        for (int s = tid; s < UNITS; s += 256) {
            int q = s % 10;
            int pp = (s / 10) % (CHUNK / 2);
            int r = s / (10 * (CHUNK / 2));
            int gy = ty0 - PADK + r;
            int gx0 = tx0 - 4 + q * 4;
            uint4 v = {0, 0, 0, 0};
            if (gy >= 0 && gy < H && gx0 >= 0 && gx0 < W)
                v = *(const uint4*)&inb[(size_t)(ck * (CHUNK / 2) + pp) * HW_ + gy * W + gx0];
            int pbase = (r * RW + q * 4) * S2 + pp;
            lds32[pbase] = v.x;
            lds32[pbase + S2] = v.y;
            lds32[pbase + 2 * S2] = v.z;
            lds32[pbase + 3 * S2] = v.w;
        }
        __syncthreads();

        short8 afr[KS * KS];
        #pragma unroll
        for (int tap = 0; tap < KS * KS; ++tap)
            afr[tap] = *(const short8*)&wr[
                ((size_t)tap * COUTP + cob + lanelo) * CINP + ck * CHUNK + laneq * 8];

        for (int tap = 0; tap < KS * KS; ++tap) {
            int ky = tap / KS, kx = tap - ky * KS;
            #pragma unroll
            for (int n = 0; n < N_TILES; ++n) {
                int rr = pg_row0 + (n >> 1) + ky;
                int pxi = (n & 1) * 16 + lanelo + (4 - PADK) + kx;
                const short8 bf = *(const short8*)&lds32[(rr * RW + pxi) * S2 + laneq * 4];
                acc[n] = __builtin_amdgcn_mfma_f32_16x16x32_bf16(afr[tap], bf, acc[n], 0, 0, 0);
            }
        }
        __syncthreads();
    }

    #pragma unroll
    for (int n = 0; n < N_TILES; ++n) {
        int x = tx0 + (n & 1) * 16 + lanelo;
        int y = ty0 + pg_row0 + (n >> 1);
        #pragma unroll
        for (int j = 0; j < 4; ++j) {
            int co = cob + laneq * 4 + j;
            if (co < coutReal) {
                float v = acc[n][j] + bias[co];
                v += (float)flow_up[((size_t)(b * 2) + co) * HW_ + y * W + x];
                outp[((size_t)b * coutReal + co) * HW_ + y * W + x] = v;
            }
        }
    }
}

// ---------------------------------------------------------------------------
extern "C" void kernel_launch(void* const* d_in, const int* in_sizes, int n_in,
                              void* d_out, int out_size, void* d_ws, size_t ws_size,
                              hipStream_t stream)
{
    const float* feats = (const float*)d_in[0];
    const float* flow  = (const float*)d_in[1];
    const float* up_w  = (const float*)d_in[2];
    const float* w1 = (const float*)d_in[3];
    const float* b1 = (const float*)d_in[4];
    const float* w2 = (const float*)d_in[5];
    const float* b2 = (const float*)d_in[6];
    const float* w3 = (const float*)d_in[7];
    const float* b3 = (const float*)d_in[8];
    const float* w4 = (const float*)d_in[9];
    const float* b4 = (const float*)d_in[10];
    float* out = (float*)d_out;

    char* ws = (char*)d_ws;
    double* flow_up = (double*)ws;                    // 3,932,160 B
    uint* wp    = (uint*)(ws + 3932160);              // warped bf16-pairs / h1
    uint* h1    = (uint*)(ws + 3932160);
    uint* corrb = (uint*)(ws + 66846720);             // corr / h2
    uint* h2    = corrb;
    uint* h3    = (uint*)(ws + 98304000);
    unsigned short* wr = (unsigned short*)(ws + 114032640);
    unsigned short* wr1 = wr;
    unsigned short* wr2 = wr + 73728;
    unsigned short* wr3 = wr + 147456;
    unsigned short* wr4 = wr + 165888;

    repack_w_kernel<<<699, 256, 0, stream>>>(w1, w2, w3, w4, wr);
    upflow_kernel<<<(B * 2 * HW_ + 255) / 256, 256, 0, stream>>>(flow, up_w, flow_up);
    warp_kernel<<<(B * HW_) / 256, 256, 0, stream>>>(feats, flow_up, wp);
    corr_kernel<<<3840, 256, 0, stream>>>(feats, wp, corrb);

    // conv1: cin 64(pad49) -> cout 128. Block: 2 co-sets x 2 rowg x 2 rows.
    conv3x3_kernel<64, 128, 2, 2, 2, 2, 3>
        <<<1920, 256, 0, stream>>>(corrb, wr1, b1, h1);
    // conv2: cin 128 -> cout 64. Block: 4 rowg x 2 rows, wave covers all 64 co.
    conv3x3_kernel<128, 64, 1, 4, 2, 2, 3>
        <<<960, 256, 0, stream>>>(h1, wr2, b2, h2);
    // conv3: cin 64 -> cout 32.
    conv3x3_kernel<64, 32, 1, 4, 1, 2, 3>
        <<<960, 256, 0, stream>>>(h2, wr3, b3, h3);
    // conv4: cin 32 -> cout 2 (pad 16), 5x5, fp32 out + bias + flow_up
    conv_mfma_kernel<32, 16, 1, 2, 5, 2>
        <<<1920, 256, 0, stream>>>(h3, wr4, b4, out, flow_up, 2);
}